// Round 11
// baseline (304.973 us; speedup 1.0000x reference)
//
#include <hip/hip_runtime.h>

// Problem constants
#define B_    32
#define CIN_  256
#define H_    64
#define W_    64
#define OH_   28
#define OW_   28
#define M_TOTAL 25088      // B*OH*OW
#define POSE_ELEMS 6422528 // B*32*OH*OW*8

typedef _Float16 f16;
typedef _Float16 f16x8 __attribute__((ext_vector_type(8)));
typedef _Float16 f16x4 __attribute__((ext_vector_type(4)));
typedef float    f32x4 __attribute__((ext_vector_type(4)));

#define GLD_LDS16(gp, lp) __builtin_amdgcn_global_load_lds( \
    (const __attribute__((address_space(1))) void*)(gp),    \
    (__attribute__((address_space(3))) void*)(lp), 16, 0, 0)

#define SBAR()     asm volatile("s_barrier" ::: "memory")
#define WAITVM0()  asm volatile("s_waitcnt vmcnt(0)" ::: "memory")
#define WAITVM12() asm volatile("s_waitcnt vmcnt(12)" ::: "memory")

// ---------------------------------------------------------------------------
// Kernel 1: x [B,CIN,H,W] fp32 -> Xt [B,H,W,CIN] fp16  (float4 global loads)
// ---------------------------------------------------------------------------
__global__ __launch_bounds__(256) void xt_kernel(const float* __restrict__ x,
                                                 f16* __restrict__ Xt)
{
    __shared__ float tile[64 * 65];
    const int t  = threadIdx.x;
    const int c0 = blockIdx.x * 64;
    const int h  = blockIdx.y;
    const int b  = blockIdx.z;

    const float* src = x + (((long)(b * CIN_ + c0)) * H_ + h) * W_;
    const int w4 = (t & 15) * 4;   // float4 column
    const int cr = t >> 4;         // 16 rows per pass
#pragma unroll
    for (int it = 0; it < 4; ++it) {
        const int c = it * 16 + cr;
        const float4 v = *(const float4*)(src + (long)c * (H_ * W_) + w4);
        tile[c * 65 + w4 + 0] = v.x;
        tile[c * 65 + w4 + 1] = v.y;
        tile[c * 65 + w4 + 2] = v.z;
        tile[c * 65 + w4 + 3] = v.w;
    }
    __syncthreads();

    f16* dst = Xt + ((long)(b * H_ + h) * W_) * CIN_ + c0;
    const int wq = t >> 4, cq = t & 15;
#pragma unroll
    for (int it = 0; it < 4; ++it) {
        const int w2 = it * 16 + wq;
        f16x4 v;
        v[0] = (f16)tile[(cq * 4 + 0) * 65 + w2];
        v[1] = (f16)tile[(cq * 4 + 1) * 65 + w2];
        v[2] = (f16)tile[(cq * 4 + 2) * 65 + w2];
        v[3] = (f16)tile[(cq * 4 + 3) * 65 + w2];
        *(f16x4*)(dst + (long)w2 * CIN_ + cq * 4) = v;
    }
}

// ---------------------------------------------------------------------------
// Kernel 2: conv_w [COUT,CIN,9,9] fp32 -> Wt in MFMA-FRAGMENT order:
//   Wt[ks=khw*4+cb][n16][h][lane][e]  (f16), flat stride 16384 f16 per ks.
//   lane = lhi*16 + llo:  n = n16*16 + llo,  k_in64 = h*32 + lhi*8 + e.
// ---------------------------------------------------------------------------
__global__ __launch_bounds__(256) void wt_kernel(const float* __restrict__ w,
                                                 f16* __restrict__ Wt)
{
    __shared__ float tile[64 * 81];
    const int t  = threadIdx.x;
    const int co = blockIdx.x >> 2;          // output channel n (0..255)
    const int cb = blockIdx.x & 3;           // cin block
    const float* src = w + ((long)co * 256 + cb * 64) * 81;
    for (int i = t; i < 64 * 81; i += 256) tile[i] = src[i];
    __syncthreads();

    const int n16 = co >> 4, llo = co & 15;
    for (int i = t; i < 648; i += 256) {     // 81 khw * 2 h * 4 lhi
        const int khw = i >> 3;
        const int rem = i & 7;
        const int h = rem >> 2, lhi = rem & 3;
        const int k0 = h * 32 + lhi * 8;
        f16x8 v;
#pragma unroll
        for (int e = 0; e < 8; ++e) v[e] = (f16)tile[(k0 + e) * 81 + khw];
        const long off = ((long)(khw * 4 + cb) * 2048 + n16 * 128 + h * 64 + lhi * 16 + llo) * 8;
        *(f16x8*)(Wt + off) = v;
    }
}

// ---------------------------------------------------------------------------
// Kernel 3: A-only-LDS split-K implicit-GEMM (256x256, BK=64, 8 waves),
// B in registers from frag-ordered Wt (L2-hot), CORRECTED wait ledger.
// Per tile t:
//   i1,i2: stage A-h0,A-h1(t+1)   [4 gld_lds]
//   WAITVM12  -> FIFO forces exactly A(t):4 (leaves bf(t):8 + A(t+1):4)
//   SBAR      -> cross-wave: all waves' A(t) resident
//   afL; Q(0,0){bf0} Q(0,1){bf1}; afH; Q(1,0){bf0};
//   i3: load bf0(t+1)  [first use Q(0,0) of t+1, ~1000cyc away];
//   Q(1,1){bf1}; i4: load bf1(t+1) [first use Q(0,1) of t+1, ~900cyc];
//   SBAR (buf-nc WAR for next tile's stages)
// B-load residency rides the COMPILER's register-dep vmcnt (G7) — our manual
// wait never touches B (R10's mistake). Reg-WAR pins i3/i4 after last bf use.
// ---------------------------------------------------------------------------
__global__ __launch_bounds__(512, 2) void gemm_kernel(const f16* __restrict__ Xt,
                                                      const f16* __restrict__ Wt,
                                                      f16* __restrict__ part,
                                                      int nsplit)
{
    __shared__ __align__(16) char ldsA[65536];   // 2 x 32KB A double-buffer

    const int t    = threadIdx.x;
    const int lane = t & 63, wave = t >> 6;

    // bijective XCD swizzle (m204)
    const int nwg = 98 * nsplit;
    const int q = nwg >> 3, r8 = nwg & 7;
    const int xcd = blockIdx.x & 7, idx = blockIdx.x >> 3;
    const int wgid = (xcd < r8 ? xcd * (q + 1) : r8 * (q + 1) + (xcd - r8) * q) + idx;
    const int sk = wgid / 98;
    const int mt = wgid - sk * 98;
    const int m0 = mt * 256;

    // uneven split-K
    const int ntb = 324 / nsplit, rem = 324 - ntb * nsplit;
    const int ksb = sk * ntb + (sk < rem ? sk : rem);
    const int NT  = ntb + (sk < rem ? 1 : 0);

    // ---- A staging source offsets (slot j = i*8+wave, rows j*8+(lane>>3)) ----
    const int csrc = ((lane & 7) ^ (lane >> 3)) * 8;
    int aoff[4];
#pragma unroll
    for (int i = 0; i < 4; ++i) {
        const int r  = (i * 8 + wave) * 8 + (lane >> 3);
        const int ga = (r & 63) + ((r >> 6) & 1) * 128 + (r >> 7) * 64;  // permA
        const int m  = m0 + ga;
        const int b   = m / 784;
        const int rem2 = m - b * 784;
        const int oh  = rem2 / 28;
        const int ow  = rem2 - oh * 28;
        aoff[i] = ((b * 64 + 2 * oh) * 64 + 2 * ow) * 256 + csrc;
    }

    // ---- fragment-read addressing (A from LDS, B from global) ----
    const int wm = wave >> 2, wn = wave & 3;   // 2x4 wave grid, 128x64 each
    int rowA[8];
#pragma unroll
    for (int mf = 0; mf < 8; ++mf) {
        const int g  = wm * 128 + mf * 16 + (lane & 15);
        const int lr = (g & 63) + ((g >> 6) & 1) * 128 + (g >> 7) * 64;  // permA (involution)
        rowA[mf] = lr * 128;
    }
    int csw[2];
    csw[0] = ((lane >> 4) * 16) ^ ((lane & 7) << 4);
    csw[1] = 64 ^ csw[0];
    const f16* Bbase = Wt + wn * 4096 + lane * 8;

    f32x4 acc[8][4];
    const f32x4 z = {0.f, 0.f, 0.f, 0.f};
#pragma unroll
    for (int i = 0; i < 8; ++i)
#pragma unroll
        for (int j = 0; j < 4; ++j) acc[i][j] = z;

#define KOFFS_A(KS, AK)                                        \
    {  const int cb_ = (KS) & 3, khw_ = (KS) >> 2;             \
       const int kh_ = khw_ / 9, kw_ = khw_ - kh_ * 9;         \
       AK = (kh_ * 64 + kw_) * 256 + cb_ * 64; }

#define STAGE_A_HALF(H, AK, NB) do {                                               \
    GLD_LDS16(Xt + aoff[2*(H)]   + (AK), ldsA + (NB)*32768 + ((2*(H))*8   + wave)*1024); \
    GLD_LDS16(Xt + aoff[2*(H)+1] + (AK), ldsA + (NB)*32768 + ((2*(H)+1)*8 + wave)*1024); } while(0)

#define LOAD_B0(KS) do {                                       \
    const f16* bp_ = Bbase + (long)(KS) * 16384;               \
    bf0[0][0] = *(const f16x8*)(bp_ + 0);                      \
    bf0[0][1] = *(const f16x8*)(bp_ + 512);                    \
    bf0[1][0] = *(const f16x8*)(bp_ + 1024);                   \
    bf0[1][1] = *(const f16x8*)(bp_ + 1536);                   \
} while(0)
#define LOAD_B1(KS) do {                                       \
    const f16* bp_ = Bbase + (long)(KS) * 16384;               \
    bf1[0][0] = *(const f16x8*)(bp_ + 2048);                   \
    bf1[0][1] = *(const f16x8*)(bp_ + 2560);                   \
    bf1[1][0] = *(const f16x8*)(bp_ + 3072);                   \
    bf1[1][1] = *(const f16x8*)(bp_ + 3584);                   \
} while(0)

#define MFMA_PAIR(MI, NI, A, Bf)                                                        \
    acc[MI][NI] = __builtin_amdgcn_mfma_f32_16x16x32_f16((A)[0], (Bf)[0], acc[MI][NI], 0,0,0); \
    acc[MI][NI] = __builtin_amdgcn_mfma_f32_16x16x32_f16((A)[1], (Bf)[1], acc[MI][NI], 0,0,0);
#define MFMA_Q(MH, NH, BF)                                          \
    MFMA_PAIR((MH)*4+0, (NH)*2+0, af[0], BF[0]) MFMA_PAIR((MH)*4+0, (NH)*2+1, af[0], BF[1]) \
    MFMA_PAIR((MH)*4+1, (NH)*2+0, af[1], BF[0]) MFMA_PAIR((MH)*4+1, (NH)*2+1, af[1], BF[1]) \
    MFMA_PAIR((MH)*4+2, (NH)*2+0, af[2], BF[0]) MFMA_PAIR((MH)*4+2, (NH)*2+1, af[2], BF[1]) \
    MFMA_PAIR((MH)*4+3, (NH)*2+0, af[3], BF[0]) MFMA_PAIR((MH)*4+3, (NH)*2+1, af[3], BF[1])

#define READ_AF(P, MH) do {                                           \
    _Pragma("unroll")                                                 \
    for (int k_ = 0; k_ < 4; ++k_) {                                  \
        af[k_][0] = *(const f16x8*)((P) + rowA[(MH)*4+k_] + csw[0]);  \
        af[k_][1] = *(const f16x8*)((P) + rowA[(MH)*4+k_] + csw[1]);  \
    } } while(0)

    f16x8 af[4][2], bf0[2][2], bf1[2][2];

    // ---- prologue: stage A(0) fully; load B(0) ----
    {
        int ak0;
        KOFFS_A(ksb, ak0);
        STAGE_A_HALF(0, ak0, 0);
        STAGE_A_HALF(1, ak0, 0);
        LOAD_B0(ksb);
        LOAD_B1(ksb);
    }

#pragma unroll 1
    for (int tt = 0; tt < NT; ++tt) {
        const int c = tt & 1, nc = c ^ 1;
        const int ksn = ksb + ((tt + 1 < NT) ? tt + 1 : tt);  // clamp (dup tail)
        int akn;
        KOFFS_A(ksn, akn);
        const char* pA = ldsA + c * 32768;

        // i1,i2: stage all of A(t+1); manual wait covers A(t) ONLY
        STAGE_A_HALF(0, akn, nc);
        STAGE_A_HALF(1, akn, nc);
        WAITVM12();   // FIFO: forces A(t):4; leaves bf(t):8 + A(t+1):4 in flight
        SBAR();       // cross-wave: every wave's A(t) resident in LDS

        READ_AF(pA, 0);
        __builtin_amdgcn_s_setprio(1);
        MFMA_Q(0, 0, bf0)
        MFMA_Q(0, 1, bf1)
        __builtin_amdgcn_s_setprio(0);
        READ_AF(pA, 1);
        __builtin_amdgcn_s_setprio(1);
        MFMA_Q(1, 0, bf0)     // last bf0(t) use
        __builtin_amdgcn_s_setprio(0);
        LOAD_B0(ksn);         // i3: bf0(t+1); ~1000cyc before first use
        __builtin_amdgcn_s_setprio(1);
        MFMA_Q(1, 1, bf1)     // last bf1(t) use
        __builtin_amdgcn_s_setprio(0);
        LOAD_B1(ksn);         // i4: bf1(t+1); ~900cyc before first use
        SBAR();               // all waves done reading buf c -> safe to stage into it
    }
    WAITVM0();   // drain dangling dup-stage/loads before epilogue

    // ---- epilogue (f16 partials) ----
    f16* base = part + (long)sk * (M_TOTAL * 256);
    const int lrow = (lane >> 4) * 4;
#pragma unroll
    for (int nf = 0; nf < 4; ++nf) {
        const int n = wn * 64 + nf * 16 + (lane & 15);
#pragma unroll
        for (int mf = 0; mf < 8; ++mf) {
            const long mrow = m0 + wm * 128 + mf * 16 + lrow;
            f16* cw = base + mrow * 256 + n;
#pragma unroll
            for (int j = 0; j < 4; ++j) cw[(long)j * 256] = (f16)acc[mf][nf][j];
        }
    }
}

// ---------------------------------------------------------------------------
// Kernel 4: f16 partial-sum + bias + squash + 3-iter routing + acts.
// ---------------------------------------------------------------------------
__global__ __launch_bounds__(256) void routing_kernel(const f16* __restrict__ part,
                                                      const float* __restrict__ bias,
                                                      const float* __restrict__ rb,
                                                      float* __restrict__ out, int nsplit)
{
    const int t   = threadIdx.x;
    const int m   = blockIdx.x * 8 + (t >> 5);
    const int cap = t & 31;
    const int b   = m / 784;
    const int rem = m - b * 784;
    const int oh  = rem / 28;
    const int ow  = rem - oh * 28;

    const float4 b0 = ((const float4*)(bias + cap * 8))[0];
    const float4 b1 = ((const float4*)(bias + cap * 8))[1];
    float v[8] = {b0.x, b0.y, b0.z, b0.w, b1.x, b1.y, b1.z, b1.w};
#pragma unroll 1
    for (int sk = 0; sk < nsplit; ++sk) {
        const f16x8 u = *(const f16x8*)(part + (long)sk * (M_TOTAL * 256) + (long)m * 256 + cap * 8);
#pragma unroll
        for (int j = 0; j < 8; ++j) v[j] += (float)u[j];
    }

    float n2 = 0.f;
#pragma unroll
    for (int j = 0; j < 8; ++j) n2 += v[j] * v[j];
    const float f = (n2 / (1.f + n2)) / sqrtf(n2 + 1e-8f);
    float votes[8];
#pragma unroll
    for (int j = 0; j < 8; ++j) votes[j] = f * v[j];

    const float4* rp = (const float4*)(rb + ((long)(cap * 28 + oh) * 28 + ow) * 8);
    const float4 r0 = rp[0], r1 = rp[1];
    const float rbv[8] = {r0.x, r0.y, r0.z, r0.w, r1.x, r1.y, r1.z, r1.w};

    float logit = 0.f;
    float poses[8];
#pragma unroll 1
    for (int it = 0; it < 3; ++it) {
        float mx = logit;
#pragma unroll
        for (int d = 16; d > 0; d >>= 1) mx = fmaxf(mx, __shfl_xor(mx, d, 32));
        const float e = __expf(logit - mx);
        float se = e;
#pragma unroll
        for (int d = 16; d > 0; d >>= 1) se += __shfl_xor(se, d, 32);
        const float c = e / se;

        float s[8];
        float sn2 = 0.f;
#pragma unroll
        for (int j = 0; j < 8; ++j) { s[j] = c * votes[j] + rbv[j]; sn2 += s[j] * s[j]; }
        const float sf = (sn2 / (1.f + sn2)) / sqrtf(sn2 + 1e-8f);
        float dot = 0.f;
#pragma unroll
        for (int j = 0; j < 8; ++j) { poses[j] = sf * s[j]; dot += votes[j] * poses[j]; }
        logit += dot;
    }

    float pn2 = 0.f;
#pragma unroll
    for (int j = 0; j < 8; ++j) pn2 += poses[j] * poses[j];
    const float act = sqrtf(pn2);

    float* po = out + (((long)(b * 32 + cap) * 28 + oh) * 28 + ow) * 8;
    float4 o0 = {poses[0], poses[1], poses[2], poses[3]};
    float4 o1 = {poses[4], poses[5], poses[6], poses[7]};
    ((float4*)po)[0] = o0;
    ((float4*)po)[1] = o1;
    out[POSE_ELEMS + ((long)(b * 32 + cap) * 28 + oh) * 28 + ow] = act;
}

// ---------------------------------------------------------------------------
extern "C" void kernel_launch(void* const* d_in, const int* in_sizes, int n_in,
                              void* d_out, int out_size, void* d_ws, size_t ws_size,
                              hipStream_t stream)
{
    const float* x      = (const float*)d_in[0];
    const float* conv_w = (const float*)d_in[1];
    const float* conv_b = (const float*)d_in[2];
    const float* rb     = (const float*)d_in[3];
    float* out          = (float*)d_out;

    char* ws = (char*)d_ws;
    f16*   Xt   = (f16*)ws;                                  // 67,108,864 B
    f16*   Wt   = (f16*)(ws + 67108864);                     // 10,616,832 B (frag order)
    const size_t base = 67108864 + 10616832;
    f16* part = (f16*)(ws + base);
    const size_t part_bytes = (size_t)M_TOTAL * 256 * 2;     // 12,845,056 B (f16)

    // nsplit=5: 490 blocks = 95.7% fill, NT=65
    int nsplit = 1;
    if      (ws_size >= base + 5 * part_bytes) nsplit = 5;
    else if (ws_size >= base + 4 * part_bytes) nsplit = 4;
    else if (ws_size >= base + 2 * part_bytes) nsplit = 2;

    xt_kernel<<<dim3(4, 64, 32), 256, 0, stream>>>(x, Xt);
    wt_kernel<<<dim3(1024), 256, 0, stream>>>(conv_w, Wt);
    gemm_kernel<<<dim3(98 * nsplit), dim3(512), 0, stream>>>(Xt, Wt, part, nsplit);
    routing_kernel<<<dim3(3136), 256, 0, stream>>>(part, conv_b, rb, out, nsplit);
}

// Round 12
// 277.795 us; speedup vs baseline: 1.0978x; 1.0978x over previous
//
#include <hip/hip_runtime.h>

// Problem constants
#define B_    32
#define CIN_  256
#define H_    64
#define W_    64
#define OH_   28
#define OW_   28
#define M_TOTAL 25088      // B*OH*OW
#define POSE_ELEMS 6422528 // B*32*OH*OW*8

typedef _Float16 f16;
typedef _Float16 f16x8 __attribute__((ext_vector_type(8)));
typedef _Float16 f16x4 __attribute__((ext_vector_type(4)));
typedef float    f32x4 __attribute__((ext_vector_type(4)));

#define GLD_LDS16(gp, lp) __builtin_amdgcn_global_load_lds( \
    (const __attribute__((address_space(1))) void*)(gp),    \
    (__attribute__((address_space(3))) void*)(lp), 16, 0, 0)

#define SBAR()    asm volatile("s_barrier" ::: "memory")
#define WAITVM0() asm volatile("s_waitcnt vmcnt(0)" ::: "memory")
#define WAITVM4() asm volatile("s_waitcnt vmcnt(4)" ::: "memory")
#define LGKM8()   asm volatile("s_waitcnt lgkmcnt(8)" ::: "memory")

// ---------------------------------------------------------------------------
// Kernel 1: x [B,CIN,H,W] fp32 -> Xt [B,H,W,CIN] fp16  (float4 global loads)
// ---------------------------------------------------------------------------
__global__ __launch_bounds__(256) void xt_kernel(const float* __restrict__ x,
                                                 f16* __restrict__ Xt)
{
    __shared__ float tile[64 * 65];
    const int t  = threadIdx.x;
    const int c0 = blockIdx.x * 64;
    const int h  = blockIdx.y;
    const int b  = blockIdx.z;

    const float* src = x + (((long)(b * CIN_ + c0)) * H_ + h) * W_;
    const int w4 = (t & 15) * 4;   // float4 column
    const int cr = t >> 4;         // 16 rows per pass
#pragma unroll
    for (int it = 0; it < 4; ++it) {
        const int c = it * 16 + cr;
        const float4 v = *(const float4*)(src + (long)c * (H_ * W_) + w4);
        tile[c * 65 + w4 + 0] = v.x;
        tile[c * 65 + w4 + 1] = v.y;
        tile[c * 65 + w4 + 2] = v.z;
        tile[c * 65 + w4 + 3] = v.w;
    }
    __syncthreads();

    f16* dst = Xt + ((long)(b * H_ + h) * W_) * CIN_ + c0;
    const int wq = t >> 4, cq = t & 15;
#pragma unroll
    for (int it = 0; it < 4; ++it) {
        const int w2 = it * 16 + wq;
        f16x4 v;
        v[0] = (f16)tile[(cq * 4 + 0) * 65 + w2];
        v[1] = (f16)tile[(cq * 4 + 1) * 65 + w2];
        v[2] = (f16)tile[(cq * 4 + 2) * 65 + w2];
        v[3] = (f16)tile[(cq * 4 + 3) * 65 + w2];
        *(f16x4*)(dst + (long)w2 * CIN_ + cq * 4) = v;
    }
}

// ---------------------------------------------------------------------------
// Kernel 2: conv_w [COUT,CIN,9,9] fp32 -> Wt [khw][COUT][CIN] fp16
// ---------------------------------------------------------------------------
__global__ __launch_bounds__(256) void wt_kernel(const float* __restrict__ w,
                                                 f16* __restrict__ Wt)
{
    __shared__ float tile[64 * 81];
    const int t  = threadIdx.x;
    const int co = blockIdx.x >> 2;
    const int c0 = (blockIdx.x & 3) * 64;
    const float* src = w + ((long)co * 256 + c0) * 81;
    for (int i = t; i < 64 * 81; i += 256) tile[i] = src[i];
    __syncthreads();
    for (int i = t; i < 64 * 81; i += 256) {
        const int khw = i >> 6, ci = i & 63;
        Wt[(long)khw * 65536 + co * 256 + c0 + ci] = (f16)tile[ci * 81 + khw];
    }
}

// ---------------------------------------------------------------------------
// Kernel 3: R9 schedule + immediate-folded LDS addressing + 2x tile unroll.
// 256x256 tile, BK=64, 8 waves; A/B double-buffered in one lds[131072].
// Stage slots per tile t (staging t+1): s1=A-h0, s2=B-h0, s3=B-h1, s4=A-h1.
//   P4(t-1) VM4 -> s1(t),s2(t) resident -> P1(t) reads afL,bf0
//   P1(t)   VM4 -> s3(t)      resident -> P2(t) reads bf1
//   P2(t)   VM4 -> s4(t)      resident -> P3(t) reads afH
// ds_read addresses: precomputed int offsets; mf-half (+16384, exact from
// permA algebra) and buffer select (+32768) folded into the 16-bit imm.
// ---------------------------------------------------------------------------
__global__ __launch_bounds__(512, 2) void gemm_kernel(const f16* __restrict__ Xt,
                                                      const f16* __restrict__ Wt,
                                                      f16* __restrict__ part,
                                                      int nsplit)
{
    __shared__ __align__(16) char lds[131072]; // A: 2x32K at 0, B: 2x32K at 64K

    const int t    = threadIdx.x;
    const int lane = t & 63, wave = t >> 6;

    // bijective XCD swizzle (m204)
    const int nwg = 98 * nsplit;
    const int q = nwg >> 3, r8 = nwg & 7;
    const int xcd = blockIdx.x & 7, idx = blockIdx.x >> 3;
    const int wgid = (xcd < r8 ? xcd * (q + 1) : r8 * (q + 1) + (xcd - r8) * q) + idx;
    const int sk = wgid / 98;
    const int mt = wgid - sk * 98;
    const int m0 = mt * 256;

    // uneven split-K
    const int ntb = 324 / nsplit, rem = 324 - ntb * nsplit;
    const int ksb = sk * ntb + (sk < rem ? sk : rem);
    const int NT  = ntb + (sk < rem ? 1 : 0);

    // ---- staging source offsets (slot j = i*8+wave, rows j*8+(lane>>3)) ----
    const int csrc = ((lane & 7) ^ (lane >> 3)) * 8;
    int aoff[4], boff[4];
#pragma unroll
    for (int i = 0; i < 4; ++i) {
        const int r  = (i * 8 + wave) * 8 + (lane >> 3);
        const int ga = (r & 63) + ((r >> 6) & 1) * 128 + (r >> 7) * 64;  // permA
        const int m  = m0 + ga;
        const int b   = m / 784;
        const int rem2 = m - b * 784;
        const int oh  = rem2 / 28;
        const int ow  = rem2 - oh * 28;
        aoff[i] = ((b * 64 + 2 * oh) * 64 + 2 * ow) * 256 + csrc;
        const int gb = (r & 31) + ((r >> 5) & 3) * 64 + (r >> 7) * 32;   // permB fwd
        boff[i] = gb * 256 + csrc;
    }

    // ---- fragment-read LDS offsets (precomputed; imm folds MH/buffer) ----
    const int wm = wave >> 2, wn = wave & 3;   // 2x4 wave grid, 128x64 each
    const int csw0 = ((lane >> 4) * 16) ^ ((lane & 7) << 4);
    const int csw1 = 64 ^ csw0;
    int aOff[4][2], bOff[4][2];
#pragma unroll
    for (int mf = 0; mf < 4; ++mf) {           // mf 0..3; +4 half is +16384 imm
        const int g  = wm * 128 + mf * 16 + (lane & 15);
        const int lr = (g & 63) + ((g >> 6) & 1) * 128 + (g >> 7) * 64;  // permA
        aOff[mf][0] = lr * 128 + csw0;
        aOff[mf][1] = lr * 128 + csw1;
    }
#pragma unroll
    for (int nf = 0; nf < 4; ++nf) {
        const int g  = wn * 64 + nf * 16 + (lane & 15);
        const int lr = (g & 31) + ((g >> 6) << 5) + ((g >> 5) & 1) * 128; // permB inv
        bOff[nf][0] = 65536 + lr * 128 + csw0;
        bOff[nf][1] = 65536 + lr * 128 + csw1;
    }

    f32x4 acc[8][4];
    const f32x4 z = {0.f, 0.f, 0.f, 0.f};
#pragma unroll
    for (int i = 0; i < 8; ++i)
#pragma unroll
        for (int j = 0; j < 4; ++j) acc[i][j] = z;

#define KOFFS(KS, AK, BK)                                      \
    {  const int cb_ = (KS) & 3, khw_ = (KS) >> 2;             \
       const int kh_ = khw_ / 9, kw_ = khw_ - kh_ * 9;         \
       AK = (kh_ * 64 + kw_) * 256 + cb_ * 64;                 \
       BK = khw_ * 65536 + cb_ * 64; }

#define STAGE_A_HALF(H, AK, NB) do {                                               \
    GLD_LDS16(Xt + aoff[2*(H)]   + (AK), lds + (NB)*32768 + ((2*(H))*8   + wave)*1024); \
    GLD_LDS16(Xt + aoff[2*(H)+1] + (AK), lds + (NB)*32768 + ((2*(H)+1)*8 + wave)*1024); } while(0)
#define STAGE_B_HALF(H, BK, NB) do {                                               \
    GLD_LDS16(Wt + boff[2*(H)]   + (BK), lds + 65536 + (NB)*32768 + ((2*(H))*8   + wave)*1024); \
    GLD_LDS16(Wt + boff[2*(H)+1] + (BK), lds + 65536 + (NB)*32768 + ((2*(H)+1)*8 + wave)*1024); } while(0)

#define MFMA_PAIR(MI, NI, A, Bf)                                                        \
    acc[MI][NI] = __builtin_amdgcn_mfma_f32_16x16x32_f16((A)[0], (Bf)[0], acc[MI][NI], 0,0,0); \
    acc[MI][NI] = __builtin_amdgcn_mfma_f32_16x16x32_f16((A)[1], (Bf)[1], acc[MI][NI], 0,0,0);
#define MFMA_Q(MH, NH, BF)                                          \
    MFMA_PAIR((MH)*4+0, (NH)*2+0, af[0], BF[0]) MFMA_PAIR((MH)*4+0, (NH)*2+1, af[0], BF[1]) \
    MFMA_PAIR((MH)*4+1, (NH)*2+0, af[1], BF[0]) MFMA_PAIR((MH)*4+1, (NH)*2+1, af[1], BF[1]) \
    MFMA_PAIR((MH)*4+2, (NH)*2+0, af[2], BF[0]) MFMA_PAIR((MH)*4+2, (NH)*2+1, af[2], BF[1]) \
    MFMA_PAIR((MH)*4+3, (NH)*2+0, af[3], BF[0]) MFMA_PAIR((MH)*4+3, (NH)*2+1, af[3], BF[1])

// Reads: literal MH selects A-half (+16384), literal C selects buffer (+32768).
#define READ_AF(MH, C) do {                                                          \
    _Pragma("unroll")                                                                \
    for (int k_ = 0; k_ < 4; ++k_) {                                                 \
        af[k_][0] = *(const f16x8*)(lds + aOff[k_][0] + (MH)*16384 + (C)*32768);     \
        af[k_][1] = *(const f16x8*)(lds + aOff[k_][1] + (MH)*16384 + (C)*32768);     \
    } } while(0)
#define READ_BF(V, NH, C) do {                                                       \
    _Pragma("unroll")                                                                \
    for (int k_ = 0; k_ < 2; ++k_) {                                                 \
        V[k_][0] = *(const f16x8*)(lds + bOff[(NH)*2+k_][0] + (C)*32768);            \
        V[k_][1] = *(const f16x8*)(lds + bOff[(NH)*2+k_][1] + (C)*32768);            \
    } } while(0)

    f16x8 af[4][2], bf0[2][2], bf1[2][2];

    // One full K-tile, buffer C (literal), staging tile KSN into buffer C^1.
#define TILE_BODY(C, KSN) do {                                      \
    int akn_, bkn_;                                                 \
    KOFFS((KSN), akn_, bkn_);                                       \
    /* P1 */                                                        \
    STAGE_A_HALF(0, akn_, (C)^1);                                   \
    WAITVM4();                                                      \
    READ_AF(0, C);                                                  \
    READ_BF(bf0, 0, C);                                             \
    LGKM8();                                                        \
    SBAR();                                                         \
    __builtin_amdgcn_s_setprio(1);                                  \
    MFMA_Q(0, 0, bf0)                                               \
    __builtin_amdgcn_s_setprio(0);                                  \
    /* P2 */                                                        \
    STAGE_B_HALF(0, bkn_, (C)^1);                                   \
    WAITVM4();                                                      \
    READ_BF(bf1, 1, C);                                             \
    SBAR();                                                         \
    __builtin_amdgcn_s_setprio(1);                                  \
    MFMA_Q(0, 1, bf1)                                               \
    __builtin_amdgcn_s_setprio(0);                                  \
    /* P3 */                                                        \
    STAGE_B_HALF(1, bkn_, (C)^1);                                   \
    READ_AF(1, C);                                                  \
    SBAR();                                                         \
    __builtin_amdgcn_s_setprio(1);                                  \
    MFMA_Q(1, 1, bf1)                                               \
    __builtin_amdgcn_s_setprio(0);                                  \
    /* P4 */                                                        \
    STAGE_A_HALF(1, akn_, (C)^1);                                   \
    WAITVM4();                                                      \
    SBAR();                                                         \
    __builtin_amdgcn_s_setprio(1);                                  \
    MFMA_Q(1, 0, bf0)                                               \
    __builtin_amdgcn_s_setprio(0);                                  \
} while(0)

    // ---- prologue: stage tile 0 in slot order s1,s2,s3,s4; cover s1,s2 ----
    {
        int ak0, bk0;
        KOFFS(ksb, ak0, bk0);
        STAGE_A_HALF(0, ak0, 0);   // s1 = A-h0
        STAGE_B_HALF(0, bk0, 0);   // s2 = B-h0
        STAGE_B_HALF(1, bk0, 0);   // s3 = B-h1
        STAGE_A_HALF(1, ak0, 0);   // s4 = A-h1
    }
    WAITVM4();   // s1(0), s2(0) resident
    SBAR();      // cross-wave: every wave's s1,s2 landed before any P1 read

    int tt = 0;
#pragma unroll 1
    for (; tt + 1 < NT; tt += 2) {
        const int ks1 = ksb + tt + 1;                              // always valid here
        TILE_BODY(0, ks1);
        const int ks2 = ksb + ((tt + 2 < NT) ? tt + 2 : tt + 1);   // clamp (dup tail)
        TILE_BODY(1, ks2);
    }
    if (tt < NT) {                 // odd NT tail: tt even -> buffer 0, dup-stage self
        const int ksl = ksb + tt;
        TILE_BODY(0, ksl);
    }
    WAITVM0();   // drain dangling dup-stage before epilogue/end

    // ---- epilogue (f16 partials) ----
    f16* base = part + (long)sk * (M_TOTAL * 256);
    const int lrow = (lane >> 4) * 4;
#pragma unroll
    for (int nf = 0; nf < 4; ++nf) {
        const int n = wn * 64 + nf * 16 + (lane & 15);
#pragma unroll
        for (int mf = 0; mf < 8; ++mf) {
            const long mrow = m0 + wm * 128 + mf * 16 + lrow;
            f16* cw = base + mrow * 256 + n;
#pragma unroll
            for (int j = 0; j < 4; ++j) cw[(long)j * 256] = (f16)acc[mf][nf][j];
        }
    }
}

// ---------------------------------------------------------------------------
// Kernel 4: f16 partial-sum + bias + squash + 3-iter routing + acts.
// ---------------------------------------------------------------------------
__global__ __launch_bounds__(256) void routing_kernel(const f16* __restrict__ part,
                                                      const float* __restrict__ bias,
                                                      const float* __restrict__ rb,
                                                      float* __restrict__ out, int nsplit)
{
    const int t   = threadIdx.x;
    const int m   = blockIdx.x * 8 + (t >> 5);
    const int cap = t & 31;
    const int b   = m / 784;
    const int rem = m - b * 784;
    const int oh  = rem / 28;
    const int ow  = rem - oh * 28;

    const float4 b0 = ((const float4*)(bias + cap * 8))[0];
    const float4 b1 = ((const float4*)(bias + cap * 8))[1];
    float v[8] = {b0.x, b0.y, b0.z, b0.w, b1.x, b1.y, b1.z, b1.w};
#pragma unroll 1
    for (int sk = 0; sk < nsplit; ++sk) {
        const f16x8 u = *(const f16x8*)(part + (long)sk * (M_TOTAL * 256) + (long)m * 256 + cap * 8);
#pragma unroll
        for (int j = 0; j < 8; ++j) v[j] += (float)u[j];
    }

    float n2 = 0.f;
#pragma unroll
    for (int j = 0; j < 8; ++j) n2 += v[j] * v[j];
    const float f = (n2 / (1.f + n2)) / sqrtf(n2 + 1e-8f);
    float votes[8];
#pragma unroll
    for (int j = 0; j < 8; ++j) votes[j] = f * v[j];

    const float4* rp = (const float4*)(rb + ((long)(cap * 28 + oh) * 28 + ow) * 8);
    const float4 r0 = rp[0], r1 = rp[1];
    const float rbv[8] = {r0.x, r0.y, r0.z, r0.w, r1.x, r1.y, r1.z, r1.w};

    float logit = 0.f;
    float poses[8];
#pragma unroll 1
    for (int it = 0; it < 3; ++it) {
        float mx = logit;
#pragma unroll
        for (int d = 16; d > 0; d >>= 1) mx = fmaxf(mx, __shfl_xor(mx, d, 32));
        const float e = __expf(logit - mx);
        float se = e;
#pragma unroll
        for (int d = 16; d > 0; d >>= 1) se += __shfl_xor(se, d, 32);
        const float c = e / se;

        float s[8];
        float sn2 = 0.f;
#pragma unroll
        for (int j = 0; j < 8; ++j) { s[j] = c * votes[j] + rbv[j]; sn2 += s[j] * s[j]; }
        const float sf = (sn2 / (1.f + sn2)) / sqrtf(sn2 + 1e-8f);
        float dot = 0.f;
#pragma unroll
        for (int j = 0; j < 8; ++j) { poses[j] = sf * s[j]; dot += votes[j] * poses[j]; }
        logit += dot;
    }

    float pn2 = 0.f;
#pragma unroll
    for (int j = 0; j < 8; ++j) pn2 += poses[j] * poses[j];
    const float act = sqrtf(pn2);

    float* po = out + (((long)(b * 32 + cap) * 28 + oh) * 28 + ow) * 8;
    float4 o0 = {poses[0], poses[1], poses[2], poses[3]};
    float4 o1 = {poses[4], poses[5], poses[6], poses[7]};
    ((float4*)po)[0] = o0;
    ((float4*)po)[1] = o1;
    out[POSE_ELEMS + ((long)(b * 32 + cap) * 28 + oh) * 28 + ow] = act;
}

// ---------------------------------------------------------------------------
extern "C" void kernel_launch(void* const* d_in, const int* in_sizes, int n_in,
                              void* d_out, int out_size, void* d_ws, size_t ws_size,
                              hipStream_t stream)
{
    const float* x      = (const float*)d_in[0];
    const float* conv_w = (const float*)d_in[1];
    const float* conv_b = (const float*)d_in[2];
    const float* rb     = (const float*)d_in[3];
    float* out          = (float*)d_out;

    char* ws = (char*)d_ws;
    f16*   Xt   = (f16*)ws;                                  // 67,108,864 B
    f16*   Wt   = (f16*)(ws + 67108864);                     // 10,616,832 B
    const size_t base = 67108864 + 10616832;
    f16* part = (f16*)(ws + base);
    const size_t part_bytes = (size_t)M_TOTAL * 256 * 2;     // 12,845,056 B (f16)

    // nsplit=5: 490 blocks = 95.7% fill, NT=65
    int nsplit = 1;
    if      (ws_size >= base + 5 * part_bytes) nsplit = 5;
    else if (ws_size >= base + 4 * part_bytes) nsplit = 4;
    else if (ws_size >= base + 2 * part_bytes) nsplit = 2;

    xt_kernel<<<dim3(4, 64, 32), 256, 0, stream>>>(x, Xt);
    wt_kernel<<<dim3(1024), 256, 0, stream>>>(conv_w, Wt);
    gemm_kernel<<<dim3(98 * nsplit), dim3(512), 0, stream>>>(Xt, Wt, part, nsplit);
    routing_kernel<<<dim3(3136), 256, 0, stream>>>(part, conv_b, rb, out, nsplit);
}

// Round 13
// 275.041 us; speedup vs baseline: 1.1088x; 1.0100x over previous
//
#include <hip/hip_runtime.h>

// Problem constants
#define B_    32
#define CIN_  256
#define H_    64
#define W_    64
#define OH_   28
#define OW_   28
#define M_TOTAL 25088      // B*OH*OW
#define POSE_ELEMS 6422528 // B*32*OH*OW*8

typedef _Float16 f16;
typedef _Float16 f16x8 __attribute__((ext_vector_type(8)));
typedef _Float16 f16x4 __attribute__((ext_vector_type(4)));
typedef float    f32x4 __attribute__((ext_vector_type(4)));

#define GLD_LDS16(gp, lp) __builtin_amdgcn_global_load_lds( \
    (const __attribute__((address_space(1))) void*)(gp),    \
    (__attribute__((address_space(3))) void*)(lp), 16, 0, 0)

#define SBAR()    asm volatile("s_barrier" ::: "memory")
#define WAITVM0() asm volatile("s_waitcnt vmcnt(0)" ::: "memory")
#define WAITVM4() asm volatile("s_waitcnt vmcnt(4)" ::: "memory")
#define LGKM8()   asm volatile("s_waitcnt lgkmcnt(8)" ::: "memory")

// ---------------------------------------------------------------------------
// Kernel 1: x [B,CIN,H,W] fp32 -> Xt [B,H,W,CIN] fp16  (float4 global loads)
// ---------------------------------------------------------------------------
__global__ __launch_bounds__(256) void xt_kernel(const float* __restrict__ x,
                                                 f16* __restrict__ Xt)
{
    __shared__ float tile[64 * 65];
    const int t  = threadIdx.x;
    const int c0 = blockIdx.x * 64;
    const int h  = blockIdx.y;
    const int b  = blockIdx.z;

    const float* src = x + (((long)(b * CIN_ + c0)) * H_ + h) * W_;
    const int w4 = (t & 15) * 4;   // float4 column
    const int cr = t >> 4;         // 16 rows per pass
#pragma unroll
    for (int it = 0; it < 4; ++it) {
        const int c = it * 16 + cr;
        const float4 v = *(const float4*)(src + (long)c * (H_ * W_) + w4);
        tile[c * 65 + w4 + 0] = v.x;
        tile[c * 65 + w4 + 1] = v.y;
        tile[c * 65 + w4 + 2] = v.z;
        tile[c * 65 + w4 + 3] = v.w;
    }
    __syncthreads();

    f16* dst = Xt + ((long)(b * H_ + h) * W_) * CIN_ + c0;
    const int wq = t >> 4, cq = t & 15;
#pragma unroll
    for (int it = 0; it < 4; ++it) {
        const int w2 = it * 16 + wq;
        f16x4 v;
        v[0] = (f16)tile[(cq * 4 + 0) * 65 + w2];
        v[1] = (f16)tile[(cq * 4 + 1) * 65 + w2];
        v[2] = (f16)tile[(cq * 4 + 2) * 65 + w2];
        v[3] = (f16)tile[(cq * 4 + 3) * 65 + w2];
        *(f16x4*)(dst + (long)w2 * CIN_ + cq * 4) = v;
    }
}

// ---------------------------------------------------------------------------
// Kernel 2: conv_w [COUT,CIN,9,9] fp32 -> Wt [khw][COUT][CIN] fp16
// ---------------------------------------------------------------------------
__global__ __launch_bounds__(256) void wt_kernel(const float* __restrict__ w,
                                                 f16* __restrict__ Wt)
{
    __shared__ float tile[64 * 81];
    const int t  = threadIdx.x;
    const int co = blockIdx.x >> 2;
    const int c0 = (blockIdx.x & 3) * 64;
    const float* src = w + ((long)co * 256 + c0) * 81;
    for (int i = t; i < 64 * 81; i += 256) tile[i] = src[i];
    __syncthreads();
    for (int i = t; i < 64 * 81; i += 256) {
        const int khw = i >> 6, ci = i & 63;
        Wt[(long)khw * 65536 + co * 256 + c0 + ci] = (f16)tile[ci * 81 + khw];
    }
}

// ---------------------------------------------------------------------------
// Kernel 3: R12 schedule with m201-density sync: 2 barriers + 2 waits / tile.
// 256x256 tile, BK=64, 8 waves; A/B double-buffered in one lds[131072].
// Stage slots per tile t (staging t+1): s1=A-h0, s2=B-h0, s3=B-h1, s4=A-h1
// (2 gld_lds each, 8 insts/tile). FIFO ledger:
//   P4(t-1): VM4 -> drains s1(t),s2(t); SBAR4  -> P1(t) reads afL,bf0
//   P2(t):   VM4 -> drains s3(t),s4(t); SBAR2  -> P2 reads bf1, P3 reads afH
// All stage->drain distances 2-3 phases (> HBM latency). Each restage is
// >=1 barrier after the last cross-wave read of its region (verified per slot).
// ds_read addrs: precomputed; MH-half (+16384) and buffer (+32768) in the imm.
// ---------------------------------------------------------------------------
__global__ __launch_bounds__(512, 2) void gemm_kernel(const f16* __restrict__ Xt,
                                                      const f16* __restrict__ Wt,
                                                      f16* __restrict__ part,
                                                      int nsplit)
{
    __shared__ __align__(16) char lds[131072]; // A: 2x32K at 0, B: 2x32K at 64K

    const int t    = threadIdx.x;
    const int lane = t & 63, wave = t >> 6;

    // bijective XCD swizzle (m204)
    const int nwg = 98 * nsplit;
    const int q = nwg >> 3, r8 = nwg & 7;
    const int xcd = blockIdx.x & 7, idx = blockIdx.x >> 3;
    const int wgid = (xcd < r8 ? xcd * (q + 1) : r8 * (q + 1) + (xcd - r8) * q) + idx;
    const int sk = wgid / 98;
    const int mt = wgid - sk * 98;
    const int m0 = mt * 256;

    // uneven split-K
    const int ntb = 324 / nsplit, rem = 324 - ntb * nsplit;
    const int ksb = sk * ntb + (sk < rem ? sk : rem);
    const int NT  = ntb + (sk < rem ? 1 : 0);

    // ---- staging source offsets (slot j = i*8+wave, rows j*8+(lane>>3)) ----
    const int csrc = ((lane & 7) ^ (lane >> 3)) * 8;
    int aoff[4], boff[4];
#pragma unroll
    for (int i = 0; i < 4; ++i) {
        const int r  = (i * 8 + wave) * 8 + (lane >> 3);
        const int ga = (r & 63) + ((r >> 6) & 1) * 128 + (r >> 7) * 64;  // permA
        const int m  = m0 + ga;
        const int b   = m / 784;
        const int rem2 = m - b * 784;
        const int oh  = rem2 / 28;
        const int ow  = rem2 - oh * 28;
        aoff[i] = ((b * 64 + 2 * oh) * 64 + 2 * ow) * 256 + csrc;
        const int gb = (r & 31) + ((r >> 5) & 3) * 64 + (r >> 7) * 32;   // permB fwd
        boff[i] = gb * 256 + csrc;
    }

    // ---- fragment-read LDS offsets (precomputed; imm folds MH/buffer) ----
    const int wm = wave >> 2, wn = wave & 3;   // 2x4 wave grid, 128x64 each
    const int csw0 = ((lane >> 4) * 16) ^ ((lane & 7) << 4);
    const int csw1 = 64 ^ csw0;
    int aOff[4][2], bOff[4][2];
#pragma unroll
    for (int mf = 0; mf < 4; ++mf) {           // mf 0..3; +4 half is +16384 imm
        const int g  = wm * 128 + mf * 16 + (lane & 15);
        const int lr = (g & 63) + ((g >> 6) & 1) * 128 + (g >> 7) * 64;  // permA
        aOff[mf][0] = lr * 128 + csw0;
        aOff[mf][1] = lr * 128 + csw1;
    }
#pragma unroll
    for (int nf = 0; nf < 4; ++nf) {
        const int g  = wn * 64 + nf * 16 + (lane & 15);
        const int lr = (g & 31) + ((g >> 6) << 5) + ((g >> 5) & 1) * 128; // permB inv
        bOff[nf][0] = 65536 + lr * 128 + csw0;
        bOff[nf][1] = 65536 + lr * 128 + csw1;
    }

    f32x4 acc[8][4];
    const f32x4 z = {0.f, 0.f, 0.f, 0.f};
#pragma unroll
    for (int i = 0; i < 8; ++i)
#pragma unroll
        for (int j = 0; j < 4; ++j) acc[i][j] = z;

#define KOFFS(KS, AK, BK)                                      \
    {  const int cb_ = (KS) & 3, khw_ = (KS) >> 2;             \
       const int kh_ = khw_ / 9, kw_ = khw_ - kh_ * 9;         \
       AK = (kh_ * 64 + kw_) * 256 + cb_ * 64;                 \
       BK = khw_ * 65536 + cb_ * 64; }

#define STAGE_A_HALF(H, AK, NB) do {                                               \
    GLD_LDS16(Xt + aoff[2*(H)]   + (AK), lds + (NB)*32768 + ((2*(H))*8   + wave)*1024); \
    GLD_LDS16(Xt + aoff[2*(H)+1] + (AK), lds + (NB)*32768 + ((2*(H)+1)*8 + wave)*1024); } while(0)
#define STAGE_B_HALF(H, BK, NB) do {                                               \
    GLD_LDS16(Wt + boff[2*(H)]   + (BK), lds + 65536 + (NB)*32768 + ((2*(H))*8   + wave)*1024); \
    GLD_LDS16(Wt + boff[2*(H)+1] + (BK), lds + 65536 + (NB)*32768 + ((2*(H)+1)*8 + wave)*1024); } while(0)

#define MFMA_PAIR(MI, NI, A, Bf)                                                        \
    acc[MI][NI] = __builtin_amdgcn_mfma_f32_16x16x32_f16((A)[0], (Bf)[0], acc[MI][NI], 0,0,0); \
    acc[MI][NI] = __builtin_amdgcn_mfma_f32_16x16x32_f16((A)[1], (Bf)[1], acc[MI][NI], 0,0,0);
#define MFMA_Q(MH, NH, BF)                                          \
    MFMA_PAIR((MH)*4+0, (NH)*2+0, af[0], BF[0]) MFMA_PAIR((MH)*4+0, (NH)*2+1, af[0], BF[1]) \
    MFMA_PAIR((MH)*4+1, (NH)*2+0, af[1], BF[0]) MFMA_PAIR((MH)*4+1, (NH)*2+1, af[1], BF[1]) \
    MFMA_PAIR((MH)*4+2, (NH)*2+0, af[2], BF[0]) MFMA_PAIR((MH)*4+2, (NH)*2+1, af[2], BF[1]) \
    MFMA_PAIR((MH)*4+3, (NH)*2+0, af[3], BF[0]) MFMA_PAIR((MH)*4+3, (NH)*2+1, af[3], BF[1])

// Reads: literal MH selects A-half (+16384), literal C selects buffer (+32768).
#define READ_AF(MH, C) do {                                                          \
    _Pragma("unroll")                                                                \
    for (int k_ = 0; k_ < 4; ++k_) {                                                 \
        af[k_][0] = *(const f16x8*)(lds + aOff[k_][0] + (MH)*16384 + (C)*32768);     \
        af[k_][1] = *(const f16x8*)(lds + aOff[k_][1] + (MH)*16384 + (C)*32768);     \
    } } while(0)
#define READ_BF(V, NH, C) do {                                                       \
    _Pragma("unroll")                                                                \
    for (int k_ = 0; k_ < 2; ++k_) {                                                 \
        V[k_][0] = *(const f16x8*)(lds + bOff[(NH)*2+k_][0] + (C)*32768);            \
        V[k_][1] = *(const f16x8*)(lds + bOff[(NH)*2+k_][1] + (C)*32768);            \
    } } while(0)

    f16x8 af[4][2], bf0[2][2], bf1[2][2];

    // One full K-tile, buffer C (literal), staging tile KSN into buffer C^1.
    // 2 barriers + 2 waits per tile (m201 density).
#define TILE_BODY(C, KSN) do {                                      \
    int akn_, bkn_;                                                 \
    KOFFS((KSN), akn_, bkn_);                                       \
    /* P1: reads covered by P4(t-1) VM4+SBAR */                     \
    STAGE_A_HALF(0, akn_, (C)^1);                                   \
    READ_AF(0, C);                                                  \
    READ_BF(bf0, 0, C);                                             \
    LGKM8();                                                        \
    __builtin_amdgcn_s_setprio(1);                                  \
    MFMA_Q(0, 0, bf0)                                               \
    __builtin_amdgcn_s_setprio(0);                                  \
    /* P2: VM4 drains s3(t),s4(t); SBAR; read bf1 */                \
    STAGE_B_HALF(0, bkn_, (C)^1);                                   \
    WAITVM4();                                                      \
    SBAR();                                                         \
    READ_BF(bf1, 1, C);                                             \
    __builtin_amdgcn_s_setprio(1);                                  \
    MFMA_Q(0, 1, bf1)                                               \
    __builtin_amdgcn_s_setprio(0);                                  \
    /* P3: read afH (s4 covered by P2 VM4+SBAR) */                  \
    STAGE_B_HALF(1, bkn_, (C)^1);                                   \
    READ_AF(1, C);                                                  \
    __builtin_amdgcn_s_setprio(1);                                  \
    MFMA_Q(1, 1, bf1)                                               \
    __builtin_amdgcn_s_setprio(0);                                  \
    /* P4: VM4 drains s1,s2(t+1); SBAR; Q(1,0) */                   \
    STAGE_A_HALF(1, akn_, (C)^1);                                   \
    WAITVM4();                                                      \
    SBAR();                                                         \
    __builtin_amdgcn_s_setprio(1);                                  \
    MFMA_Q(1, 0, bf0)                                               \
    __builtin_amdgcn_s_setprio(0);                                  \
} while(0)

    // ---- prologue: stage tile 0 in slot order s1,s2,s3,s4; cover s1,s2 ----
    {
        int ak0, bk0;
        KOFFS(ksb, ak0, bk0);
        STAGE_A_HALF(0, ak0, 0);   // s1 = A-h0
        STAGE_B_HALF(0, bk0, 0);   // s2 = B-h0
        STAGE_B_HALF(1, bk0, 0);   // s3 = B-h1
        STAGE_A_HALF(1, ak0, 0);   // s4 = A-h1
    }
    WAITVM4();   // s1(0), s2(0) resident (acts as P4(t-1) wait)
    SBAR();      // cross-wave: every wave's s1,s2 landed before any P1 read

    int tt = 0;
#pragma unroll 1
    for (; tt + 1 < NT; tt += 2) {
        const int ks1 = ksb + tt + 1;                              // always valid here
        TILE_BODY(0, ks1);
        const int ks2 = ksb + ((tt + 2 < NT) ? tt + 2 : tt + 1);   // clamp (dup tail)
        TILE_BODY(1, ks2);
    }
    if (tt < NT) {                 // odd NT tail: tt even -> buffer 0, dup-stage self
        const int ksl = ksb + tt;
        TILE_BODY(0, ksl);
    }
    WAITVM0();   // drain dangling dup-stage before epilogue/end

    // ---- epilogue (f16 partials) ----
    f16* base = part + (long)sk * (M_TOTAL * 256);
    const int lrow = (lane >> 4) * 4;
#pragma unroll
    for (int nf = 0; nf < 4; ++nf) {
        const int n = wn * 64 + nf * 16 + (lane & 15);
#pragma unroll
        for (int mf = 0; mf < 8; ++mf) {
            const long mrow = m0 + wm * 128 + mf * 16 + lrow;
            f16* cw = base + mrow * 256 + n;
#pragma unroll
            for (int j = 0; j < 4; ++j) cw[(long)j * 256] = (f16)acc[mf][nf][j];
        }
    }
}

// ---------------------------------------------------------------------------
// Kernel 4: f16 partial-sum + bias + squash + 3-iter routing + acts.
// ---------------------------------------------------------------------------
__global__ __launch_bounds__(256) void routing_kernel(const f16* __restrict__ part,
                                                      const float* __restrict__ bias,
                                                      const float* __restrict__ rb,
                                                      float* __restrict__ out, int nsplit)
{
    const int t   = threadIdx.x;
    const int m   = blockIdx.x * 8 + (t >> 5);
    const int cap = t & 31;
    const int b   = m / 784;
    const int rem = m - b * 784;
    const int oh  = rem / 28;
    const int ow  = rem - oh * 28;

    const float4 b0 = ((const float4*)(bias + cap * 8))[0];
    const float4 b1 = ((const float4*)(bias + cap * 8))[1];
    float v[8] = {b0.x, b0.y, b0.z, b0.w, b1.x, b1.y, b1.z, b1.w};
#pragma unroll 1
    for (int sk = 0; sk < nsplit; ++sk) {
        const f16x8 u = *(const f16x8*)(part + (long)sk * (M_TOTAL * 256) + (long)m * 256 + cap * 8);
#pragma unroll
        for (int j = 0; j < 8; ++j) v[j] += (float)u[j];
    }

    float n2 = 0.f;
#pragma unroll
    for (int j = 0; j < 8; ++j) n2 += v[j] * v[j];
    const float f = (n2 / (1.f + n2)) / sqrtf(n2 + 1e-8f);
    float votes[8];
#pragma unroll
    for (int j = 0; j < 8; ++j) votes[j] = f * v[j];

    const float4* rp = (const float4*)(rb + ((long)(cap * 28 + oh) * 28 + ow) * 8);
    const float4 r0 = rp[0], r1 = rp[1];
    const float rbv[8] = {r0.x, r0.y, r0.z, r0.w, r1.x, r1.y, r1.z, r1.w};

    float logit = 0.f;
    float poses[8];
#pragma unroll 1
    for (int it = 0; it < 3; ++it) {
        float mx = logit;
#pragma unroll
        for (int d = 16; d > 0; d >>= 1) mx = fmaxf(mx, __shfl_xor(mx, d, 32));
        const float e = __expf(logit - mx);
        float se = e;
#pragma unroll
        for (int d = 16; d > 0; d >>= 1) se += __shfl_xor(se, d, 32);
        const float c = e / se;

        float s[8];
        float sn2 = 0.f;
#pragma unroll
        for (int j = 0; j < 8; ++j) { s[j] = c * votes[j] + rbv[j]; sn2 += s[j] * s[j]; }
        const float sf = (sn2 / (1.f + sn2)) / sqrtf(sn2 + 1e-8f);
        float dot = 0.f;
#pragma unroll
        for (int j = 0; j < 8; ++j) { poses[j] = sf * s[j]; dot += votes[j] * poses[j]; }
        logit += dot;
    }

    float pn2 = 0.f;
#pragma unroll
    for (int j = 0; j < 8; ++j) pn2 += poses[j] * poses[j];
    const float act = sqrtf(pn2);

    float* po = out + (((long)(b * 32 + cap) * 28 + oh) * 28 + ow) * 8;
    float4 o0 = {poses[0], poses[1], poses[2], poses[3]};
    float4 o1 = {poses[4], poses[5], poses[6], poses[7]};
    ((float4*)po)[0] = o0;
    ((float4*)po)[1] = o1;
    out[POSE_ELEMS + ((long)(b * 32 + cap) * 28 + oh) * 28 + ow] = act;
}

// ---------------------------------------------------------------------------
extern "C" void kernel_launch(void* const* d_in, const int* in_sizes, int n_in,
                              void* d_out, int out_size, void* d_ws, size_t ws_size,
                              hipStream_t stream)
{
    const float* x      = (const float*)d_in[0];
    const float* conv_w = (const float*)d_in[1];
    const float* conv_b = (const float*)d_in[2];
    const float* rb     = (const float*)d_in[3];
    float* out          = (float*)d_out;

    char* ws = (char*)d_ws;
    f16*   Xt   = (f16*)ws;                                  // 67,108,864 B
    f16*   Wt   = (f16*)(ws + 67108864);                     // 10,616,832 B
    const size_t base = 67108864 + 10616832;
    f16* part = (f16*)(ws + base);
    const size_t part_bytes = (size_t)M_TOTAL * 256 * 2;     // 12,845,056 B (f16)

    // nsplit=5: 490 blocks = 95.7% fill, NT=65
    int nsplit = 1;
    if      (ws_size >= base + 5 * part_bytes) nsplit = 5;
    else if (ws_size >= base + 4 * part_bytes) nsplit = 4;
    else if (ws_size >= base + 2 * part_bytes) nsplit = 2;

    xt_kernel<<<dim3(4, 64, 32), 256, 0, stream>>>(x, Xt);
    wt_kernel<<<dim3(1024), 256, 0, stream>>>(conv_w, Wt);
    gemm_kernel<<<dim3(98 * nsplit), dim3(512), 0, stream>>>(Xt, Wt, part, nsplit);
    routing_kernel<<<dim3(3136), 256, 0, stream>>>(part, conv_b, rb, out, nsplit);
}